// Round 3
// baseline (347.414 us; speedup 1.0000x reference)
//
#include <hip/hip_runtime.h>

// x: (64, 256, 56, 56) fp32.  Channel-block n:m sparsity:
//   mask1: keep top-2 of every 4 channels (ties kept, >= 2nd-largest |x|)
//   mask2: on residual (kept entries zeroed), keep top-1 of every 8 channels
//   out = x * (mask1 | mask2)
// One thread = 4 spatial positions (float4) x 8 channels (one m2 block).
// R4: plain loads — FETCH halved (L3 hits), dur flat -> reads not critical.
// R5: plain stores — ~neutral (±1%). Kernel pinned at ~125 us moving 308-411
//     MB = 2.4-3.3 TB/s while fillBuffer does 6.6 TB/s in the same run ->
//     rate problem, not bytes problem.
// R6 (this round): stream-locality restructure. Before: each block touched
//     8 streams x 4 KB then died (~12K live 4 KB islands chip-wide, no
//     sequential run for the DRAM controllers). Now each block owns
//     8 channel rows x 16 KB contiguous, walked by a k-loop (4 x 256 thr x
//     float4). Same thread-level coalescing, 4x longer per-stream runs,
//     grid 6272 -> 1568 blocks (49 x 32, exact cover).

#define N_IMG   64
#define C_CH    256
#define HW      3136          // 56*56
#define HW4     784           // HW / 4
#define CH_OCT  32            // C / 8
#define COLS    (N_IMG * HW4) // 50176 float4-columns per channel row
#define KCH     4             // float4-columns per thread per channel row
#define BLK     256

typedef float vfloat4 __attribute__((ext_vector_type(4)));

__device__ __forceinline__ float second_largest4(float a, float b, float c, float d) {
    float mab = fmaxf(a, b), nab = fminf(a, b);
    float mcd = fmaxf(c, d), ncd = fminf(c, d);
    return fmaxf(fminf(mab, mcd), fmaxf(nab, ncd));
}

__global__ __launch_bounds__(BLK) void sparsity_kernel(const float* __restrict__ x,
                                                       float* __restrict__ out) {
    const int cb   = blockIdx.y;                          // channel octet 0..31
    const int col0 = blockIdx.x * (BLK * KCH) + threadIdx.x;

    // unroll 2: lets the compiler overlap k+1's loads with k's compute
    // without hoisting all 4 iterations' data (128 VGPRs) at once.
    #pragma unroll 2
    for (int k = 0; k < KCH; ++k) {
        const int col = col0 + k * BLK;   // flattened (n, hw4) column index
        const int n   = col / HW4;        // compile-time div -> magic mul
        const int hw4 = col - n * HW4;

        const size_t base = (size_t)n * (C_CH * HW) + (size_t)cb * (8 * HW)
                          + (size_t)hw4 * 4;
        const vfloat4* px = (const vfloat4*)(x + base);
        vfloat4* po = (vfloat4*)(out + base);

        // Load 8 channels x 4 spatial (coalesced 1 KB per wave per instr).
        vfloat4 v[8];
        #pragma unroll
        for (int c = 0; c < 8; ++c) {
            v[c] = px[c * (HW / 4)];
        }

        // Mask in place, one spatial element at a time.
        #pragma unroll
        for (int e = 0; e < 4; ++e) {
            float a[8];
            #pragma unroll
            for (int c = 0; c < 8; ++c) a[c] = fabsf(v[c][e]);

            const float thr1a = second_largest4(a[0], a[1], a[2], a[3]);
            const float thr1b = second_largest4(a[4], a[5], a[6], a[7]);

            float res[8];
            bool  m1[8];
            #pragma unroll
            for (int c = 0; c < 4; ++c) { m1[c] = a[c] >= thr1a; res[c] = m1[c] ? 0.0f : a[c]; }
            #pragma unroll
            for (int c = 4; c < 8; ++c) { m1[c] = a[c] >= thr1b; res[c] = m1[c] ? 0.0f : a[c]; }

            float thr2 = res[0];
            #pragma unroll
            for (int c = 1; c < 8; ++c) thr2 = fmaxf(thr2, res[c]);

            #pragma unroll
            for (int c = 0; c < 8; ++c) {
                const bool keep = m1[c] | (res[c] >= thr2);
                v[c][e] = keep ? v[c][e] : 0.0f;
            }
        }

        #pragma unroll
        for (int c = 0; c < 8; ++c) {
            po[c * (HW / 4)] = v[c];
        }
    }
}

extern "C" void kernel_launch(void* const* d_in, const int* in_sizes, int n_in,
                              void* d_out, int out_size, void* d_ws, size_t ws_size,
                              hipStream_t stream) {
    const float* x = (const float*)d_in[0];
    float* out = (float*)d_out;
    dim3 grid(COLS / (BLK * KCH), CH_OCT);  // 49 x 32 = 1568 blocks, exact
    sparsity_kernel<<<grid, 256, 0, stream>>>(x, out);
}

// Round 4
// 336.619 us; speedup vs baseline: 1.0321x; 1.0321x over previous
//
#include <hip/hip_runtime.h>

// x: (64, 256, 56, 56) fp32.  Channel-block n:m sparsity:
//   mask1: keep top-2 of every 4 channels (ties kept, >= 2nd-largest |x|)
//   mask2: on residual (kept entries zeroed), keep top-1 of every 8 channels
//   out = x * (mask1 | mask2)
// One thread = 4 spatial positions (float4) x 8 channels (one m2 block).
// Findings so far (R4-R6): reads off critical path (L3 hits bought nothing);
//   store cache mode ~neutral; run length 4 KB vs 16 KB neutral; nt/nt is
//   the best memory mode (R0, ~18 us better than any cached variant).
// R7 (this round): attack the per-wave burst-join pattern. R0 waves did
//   {8 loads -> vmcnt(0) join -> compute -> 8 stores -> die}: the memory
//   pipe drains once per wave. Now each wave walks KCH=4 column-steps with
//   an explicit register double buffer: loads(k+1) are issued BEFORE
//   compute(k)/stores(k), so >=8 nt loads stay in flight continuously
//   (compiler emits counted vmcnt, legal via __restrict__). nt on both
//   paths, identical mask math.

#define N_IMG   64
#define C_CH    256
#define HW      3136          // 56*56
#define HW4     784           // HW / 4
#define CH_OCT  32            // C / 8
#define COLS    (N_IMG * HW4) // 50176 float4-columns per channel row
#define KCH     4             // column-steps per thread
#define BLK     256

typedef float vfloat4 __attribute__((ext_vector_type(4)));

__device__ __forceinline__ float second_largest4(float a, float b, float c, float d) {
    float mab = fmaxf(a, b), nab = fminf(a, b);
    float mcd = fmaxf(c, d), ncd = fminf(c, d);
    return fmaxf(fminf(mab, mcd), fmaxf(nab, ncd));
}

// In-place mask of 8 channels x 4 spatial.
__device__ __forceinline__ void mask_oct(vfloat4 v[8]) {
    #pragma unroll
    for (int e = 0; e < 4; ++e) {
        float a[8];
        #pragma unroll
        for (int c = 0; c < 8; ++c) a[c] = fabsf(v[c][e]);

        const float thr1a = second_largest4(a[0], a[1], a[2], a[3]);
        const float thr1b = second_largest4(a[4], a[5], a[6], a[7]);

        float res[8];
        bool  m1[8];
        #pragma unroll
        for (int c = 0; c < 4; ++c) { m1[c] = a[c] >= thr1a; res[c] = m1[c] ? 0.0f : a[c]; }
        #pragma unroll
        for (int c = 4; c < 8; ++c) { m1[c] = a[c] >= thr1b; res[c] = m1[c] ? 0.0f : a[c]; }

        float thr2 = res[0];
        #pragma unroll
        for (int c = 1; c < 8; ++c) thr2 = fmaxf(thr2, res[c]);

        #pragma unroll
        for (int c = 0; c < 8; ++c) {
            const bool keep = m1[c] | (res[c] >= thr2);
            v[c][e] = keep ? v[c][e] : 0.0f;
        }
    }
}

__global__ __launch_bounds__(BLK) void sparsity_kernel(const float* __restrict__ x,
                                                       float* __restrict__ out) {
    const int cb   = blockIdx.y;                          // channel octet 0..31
    const int col0 = blockIdx.x * (BLK * KCH) + threadIdx.x;

    // Precompute the 4 step bases (column -> (n, hw4) -> byte offset).
    size_t base[KCH];
    #pragma unroll
    for (int k = 0; k < KCH; ++k) {
        const int col = col0 + k * BLK;
        const int n   = col / HW4;        // const divisor -> magic mul
        const int hw4 = col - n * HW4;
        base[k] = (size_t)n * (C_CH * HW) + (size_t)cb * (8 * HW) + (size_t)hw4 * 4;
    }

    vfloat4 cur[8], nxt[8];

    // Prologue: fill the pipe for step 0.
    {
        const vfloat4* px = (const vfloat4*)(x + base[0]);
        #pragma unroll
        for (int c = 0; c < 8; ++c)
            cur[c] = __builtin_nontemporal_load(&px[c * (HW / 4)]);
    }

    #pragma unroll
    for (int k = 0; k < KCH; ++k) {
        // Issue next step's loads FIRST so they overlap this step's
        // compute + stores (x/out are __restrict__ -> reorder is legal).
        if (k + 1 < KCH) {
            const vfloat4* px = (const vfloat4*)(x + base[k + 1]);
            #pragma unroll
            for (int c = 0; c < 8; ++c)
                nxt[c] = __builtin_nontemporal_load(&px[c * (HW / 4)]);
        }

        mask_oct(cur);

        {
            vfloat4* po = (vfloat4*)(out + base[k]);
            #pragma unroll
            for (int c = 0; c < 8; ++c)
                __builtin_nontemporal_store(cur[c], &po[c * (HW / 4)]);
        }

        // Rotate buffers (register renaming in the unrolled code, no moves).
        #pragma unroll
        for (int c = 0; c < 8; ++c) cur[c] = nxt[c];
    }
}

extern "C" void kernel_launch(void* const* d_in, const int* in_sizes, int n_in,
                              void* d_out, int out_size, void* d_ws, size_t ws_size,
                              hipStream_t stream) {
    const float* x = (const float*)d_in[0];
    float* out = (float*)d_out;
    dim3 grid(COLS / (BLK * KCH), CH_OCT);  // 49 x 32 = 1568 blocks, exact
    sparsity_kernel<<<grid, 256, 0, stream>>>(x, out);
}

// Round 5
// 328.383 us; speedup vs baseline: 1.0580x; 1.0251x over previous
//
#include <hip/hip_runtime.h>

// x: (64, 256, 56, 56) fp32.  Channel-block n:m sparsity:
//   mask1: keep top-2 of every 4 channels (ties kept, >= 2nd-largest |x|)
//   mask2: on residual (kept entries zeroed), keep top-1 of every 8 channels
//   out = x * (mask1 | mask2)
// Eliminated so far: L3-resident reads (R4: FETCH halved, dur flat), store
//   cache mode (R5), DRAM run length (R6), per-wave load pipelining (R7).
//   Kernel pinned at ~107-126 us moving 411 MB (~3.3-3.9 TB/s) while the
//   same-run fill does 6.6 TB/s and float4 copy does 6.29 TB/s.
// R8 (this round): the last structural difference vs a copy — wave-level
//   access SHAPE. Before: every wave touched 8 isolated 1 KB islands at
//   12.5 KB channel stride. Now: a block owns a contiguous-per-channel slab
//   (8 channel half-rows x 6,272 B), streams it LINEARLY global->LDS,
//   masks via column reads from LDS (+1-float4 pad, conflict-free b128),
//   then streams LDS->global LINEARLY. Global traffic is dense sequential
//   sweeps, copy-shaped. 50,304 B static LDS -> 2 blocks/CU (16 waves/CU)
//   so resident blocks' phases stagger and the memory pipe stays fed.

#define N_IMG     64
#define C_CH      256
#define HW        3136            // 56*56
#define HW4       784             // float4s per channel row
#define CH_OCT    32              // C / 8
#define HALF_F4   392             // float4s per channel half-row
#define LDS_STR   393             // +1 float4 pad -> conflict-free columns
#define SLAB_F4   (8 * HALF_F4)   // 3136 float4s = 50,176 B per slab
#define BLK       512

typedef float vfloat4 __attribute__((ext_vector_type(4)));

__device__ __forceinline__ float second_largest4(float a, float b, float c, float d) {
    float mab = fmaxf(a, b), nab = fminf(a, b);
    float mcd = fmaxf(c, d), ncd = fminf(c, d);
    return fmaxf(fminf(mab, mcd), fmaxf(nab, ncd));
}

// In-place mask of 8 channels x 4 spatial.
__device__ __forceinline__ void mask_oct(vfloat4 v[8]) {
    #pragma unroll
    for (int e = 0; e < 4; ++e) {
        float a[8];
        #pragma unroll
        for (int c = 0; c < 8; ++c) a[c] = fabsf(v[c][e]);

        const float thr1a = second_largest4(a[0], a[1], a[2], a[3]);
        const float thr1b = second_largest4(a[4], a[5], a[6], a[7]);

        float res[8];
        bool  m1[8];
        #pragma unroll
        for (int c = 0; c < 4; ++c) { m1[c] = a[c] >= thr1a; res[c] = m1[c] ? 0.0f : a[c]; }
        #pragma unroll
        for (int c = 4; c < 8; ++c) { m1[c] = a[c] >= thr1b; res[c] = m1[c] ? 0.0f : a[c]; }

        float thr2 = res[0];
        #pragma unroll
        for (int c = 1; c < 8; ++c) thr2 = fmaxf(thr2, res[c]);

        #pragma unroll
        for (int c = 0; c < 8; ++c) {
            const bool keep = m1[c] | (res[c] >= thr2);
            v[c][e] = keep ? v[c][e] : 0.0f;
        }
    }
}

__global__ __launch_bounds__(BLK) void sparsity_kernel(const float* __restrict__ x,
                                                       float* __restrict__ out) {
    __shared__ vfloat4 slab[8 * LDS_STR];   // 50,304 B

    const int h  = blockIdx.x & 1;          // half-row 0/1
    const int cb = blockIdx.x >> 1;         // channel octet 0..31
    const int n  = blockIdx.y;              // image
    const int t  = threadIdx.x;

    // float4 base of this slab in global memory
    const size_t gbase = (size_t)n * (C_CH * HW4) + (size_t)cb * (8 * HW4)
                       + (size_t)h * HALF_F4;
    const vfloat4* gx = (const vfloat4*)x + gbase;
    vfloat4*       go = (vfloat4*)out + gbase;

    // Phase 1: linear global -> LDS (dense sequential sweep, copy-shaped).
    #pragma unroll
    for (int j = 0; j < 7; ++j) {
        const int f = j * BLK + t;               // slab float4 index
        if (f < SLAB_F4) {
            const int c   = f / HALF_F4;         // const divisor -> magic mul
            const int col = f - c * HALF_F4;
            slab[c * LDS_STR + col] =
                __builtin_nontemporal_load(&gx[(size_t)c * HW4 + col]);
        }
    }
    __syncthreads();

    // Phase 2: column-gather from LDS, mask, write back in place.
    if (t < HALF_F4) {
        vfloat4 v[8];
        #pragma unroll
        for (int c = 0; c < 8; ++c) v[c] = slab[c * LDS_STR + t];
        mask_oct(v);
        #pragma unroll
        for (int c = 0; c < 8; ++c) slab[c * LDS_STR + t] = v[c];
    }
    __syncthreads();

    // Phase 3: linear LDS -> global (dense sequential sweep).
    #pragma unroll
    for (int j = 0; j < 7; ++j) {
        const int f = j * BLK + t;
        if (f < SLAB_F4) {
            const int c   = f / HALF_F4;
            const int col = f - c * HALF_F4;
            __builtin_nontemporal_store(slab[c * LDS_STR + col],
                                        &go[(size_t)c * HW4 + col]);
        }
    }
}

extern "C" void kernel_launch(void* const* d_in, const int* in_sizes, int n_in,
                              void* d_out, int out_size, void* d_ws, size_t ws_size,
                              hipStream_t stream) {
    const float* x = (const float*)d_in[0];
    float* out = (float*)d_out;
    dim3 grid(2 * CH_OCT, N_IMG);   // (half, octet) x image = 64 x 64 = 4096 blocks
    sparsity_kernel<<<grid, BLK, 0, stream>>>(x, out);
}